// Round 9
// baseline (28481.308 us; speedup 1.0000x reference)
//
#include <hip/hip_runtime.h>

// Problem constants
#define BATCH   16
#define NPTS    32768
#define NPOINT  2048
#define C_FEAT  128

#define NTH     1024
#define PPT     32            // points per thread
#define NW      16            // waves per block

// ===========================================================================
// Round 9 = round 8 + two changes:
//  (1) __launch_bounds__(NTH, 4): 4 waves/SIMD -> 128 VGPR cap (was 64).
//      r8's spill evidence: WRITE_SIZE 13.7MB (kernel writes 128KB),
//      VGPR_Count==64 with ~75 live regs -> bbox/chunkmax/dmin in scratch on
//      the per-step critical path => 97% stall. 128 VGPRs fits everything.
//  (2) wave-uniform skip via __any(): skipping needs the bbox proof; running
//      the exact update never does. Lanes that could skip but run produce
//      bit-identical dmin. Kills divergence in the update branch.
// Exactness invariants unchanged from r8 (verified r7 FMA pipeline, bbox
// prune margin 0.999 >> 4ulp, two-pass first-occurrence argmax).
// ===========================================================================

__device__ inline unsigned part4(unsigned v) {  // spread 4 bits to every 3rd
  return (v & 1u) | ((v & 2u) << 2) | ((v & 4u) << 4) | ((v & 8u) << 6);
}
__device__ inline int cell_of(float x, float y, float z) {
  int qx = min(15, max(0, (int)((x + 5.0f) * 1.6f)));
  int qy = min(15, max(0, (int)((y + 5.0f) * 1.6f)));
  int qz = min(15, max(0, (int)((z + 5.0f) * 1.6f)));
  return (int)(part4((unsigned)qx) | (part4((unsigned)qy) << 1) |
               (part4((unsigned)qz) << 2));          // 12-bit Morton
}

// ---------------------------------------------------------------------------
// Spatial counting sort (one block per batch): Morton-4/4/4 cells, LDS
// histogram + block scan + scatter into chunk-transposed layout:
// sorted position p -> t_idx = (p&31)*1024 + (p>>5), so thread j's chunk
// (sorted positions j*32..j*32+31) is read coalesced at [k*1024 + j].
// ---------------------------------------------------------------------------
__global__ __launch_bounds__(NTH, 4) void sort_kernel(
    const float* __restrict__ xyz, float* __restrict__ x_t,
    float* __restrict__ y_t, float* __restrict__ z_t,
    int* __restrict__ oidx_t, int* __restrict__ pos0) {
  const int b = blockIdx.x, t = threadIdx.x, lane = t & 63;
  const float* __restrict__ base = xyz + (size_t)b * NPTS * 3;
  __shared__ unsigned bins[4096];
  __shared__ unsigned wsum[NW];

  for (int i = t; i < 4096; i += NTH) bins[i] = 0u;
  __syncthreads();

  // histogram
  for (int k = 0; k < PPT; ++k) {
    const int p = k * NTH + t;
    const float x = base[p * 3], y = base[p * 3 + 1], z = base[p * 3 + 2];
    atomicAdd(&bins[cell_of(x, y, z)], 1u);
  }
  __syncthreads();

  // exclusive scan over 4096 bins (thread owns bins[4t..4t+4))
  unsigned c0 = bins[4 * t], c1 = bins[4 * t + 1], c2 = bins[4 * t + 2],
           c3 = bins[4 * t + 3];
  const unsigned mysum = c0 + c1 + c2 + c3;
  unsigned acc = mysum;                       // wave-inclusive scan
#pragma unroll
  for (int d = 1; d < 64; d <<= 1) {
    unsigned n = __shfl_up(acc, d);
    if (lane >= d) acc += n;
  }
  if (lane == 63) wsum[t >> 6] = acc;
  __syncthreads();
  unsigned woff = 0;
  for (int w = 0; w < (t >> 6); ++w) woff += wsum[w];
  unsigned run = woff + acc - mysum;          // block-exclusive for this thread
  bins[4 * t] = run; run += c0;
  bins[4 * t + 1] = run; run += c1;
  bins[4 * t + 2] = run; run += c2;
  bins[4 * t + 3] = run;
  __syncthreads();

  // scatter
  for (int k = 0; k < PPT; ++k) {
    const int p = k * NTH + t;
    const float x = base[p * 3], y = base[p * 3 + 1], z = base[p * 3 + 2];
    const unsigned pos = atomicAdd(&bins[cell_of(x, y, z)], 1u);
    const int tix = (int)(((pos & 31u) << 10) | (pos >> 5));
    const size_t o = (size_t)b * NPTS + tix;
    x_t[o] = x; y_t[o] = y; z_t[o] = z; oidx_t[o] = p;
    if (p == 0) pos0[b] = (int)pos;
  }
}

// ---------------------------------------------------------------------------
// Lazy FPS (one block per batch), 128-VGPR budget.
// ---------------------------------------------------------------------------
__global__ __launch_bounds__(NTH, 4) void fps_kernel(
    const float* __restrict__ x_t, const float* __restrict__ y_t,
    const float* __restrict__ z_t, const int* __restrict__ oidx_t,
    const int* __restrict__ pos0, int* __restrict__ fps_idx) {
  const int b = blockIdx.x, t = threadIdx.x;
  const int lane = t & 63, w = t >> 6;
  const float* __restrict__ X = x_t + (size_t)b * NPTS;
  const float* __restrict__ Y = y_t + (size_t)b * NPTS;
  const float* __restrict__ Z = z_t + (size_t)b * NPTS;
  const int* __restrict__ OI = oidx_t + (size_t)b * NPTS;

  __shared__ float s_wmax[NW];
  __shared__ int   s_gkey[2];

  // chunk bbox + dmin init
  float dmin[PPT];
  float bxl = 1e30f, bxh = -1e30f, byl = 1e30f, byh = -1e30f,
        bzl = 1e30f, bzh = -1e30f;
#pragma unroll
  for (int k = 0; k < PPT; ++k) {
    const int a = (k << 10) + t;
    const float x = X[a], y = Y[a], z = Z[a];
    bxl = fminf(bxl, x); bxh = fmaxf(bxh, x);
    byl = fminf(byl, y); byh = fmaxf(byh, y);
    bzl = fminf(bzl, z); bzh = fmaxf(bzh, z);
    dmin[k] = 1e10f;
  }
  float chunkmax = 1e10f;
  int far_orig = 0;
  int spos = pos0[b];
  if (t == 0) { s_gkey[0] = 0x7fffffff; s_gkey[1] = 0x7fffffff; }
  __syncthreads();

  for (int s = 0; s < NPOINT; ++s) {
    if (t == 0) fps_idx[b * NPOINT + s] = far_orig;

    const int ca = ((spos & 31) << 10) | (spos >> 5);
    const float cx = X[ca], cy = Y[ca], cz = Z[ca];   // broadcast loads

    // prune: min possible dist^2 from centroid to chunk bbox
    const float ddx = fmaxf(fmaxf(bxl - cx, cx - bxh), 0.0f);
    const float ddy = fmaxf(fmaxf(byl - cy, cy - byh), 0.0f);
    const float ddz = fmaxf(fmaxf(bzl - cz, cz - bzh), 0.0f);
    const float r2 = ddx * ddx + ddy * ddy + ddz * ddz;

    // wave-uniform: run the (exact) update if ANY lane in the wave needs it.
    // Running an update that could have been skipped is still the exact
    // reference computation -> bit-identical dmin either way.
    const bool need = !(r2 * 0.999f > chunkmax);
    if (__any(need)) {
      float vm = -1.0f;
#pragma unroll
      for (int k = 0; k < PPT; ++k) {
        const int a = (k << 10) + t;
        const float dx = X[a] - cx;
        const float dy = Y[a] - cy;
        const float dz = Z[a] - cz;
        // EXACT reference pipeline (verified round 7):
        const float d = __builtin_fmaf(dz, dz, __builtin_fmaf(dy, dy, dx * dx));
        const float nd = fminf(dmin[k], d);
        dmin[k] = nd;
        vm = fmaxf(vm, nd);
      }
      chunkmax = vm;
    }

    // pass 1: block max of per-chunk maxima
    float v = chunkmax;
#pragma unroll
    for (int off = 32; off > 0; off >>= 1) v = fmaxf(v, __shfl_xor(v, off));
    if (lane == 0) s_wmax[w] = v;
    __syncthreads();                                  // barrier 1
    float M = s_wmax[lane & 15];
#pragma unroll
    for (int off = 8; off > 0; off >>= 1) M = fmaxf(M, __shfl_xor(M, off));

    if (t == 0) s_gkey[(s + 1) & 1] = 0x7fffffff;     // reset ping-pong slot

    // pass 2: min (orig_idx, sorted_pos) key among dmin == M
    if (chunkmax == M) {
#pragma unroll
      for (int k = 0; k < PPT; ++k) {
        if (dmin[k] == M) {
          const int oi = OI[(k << 10) + t];
          const int p = (t << 5) | k;                 // sorted position
          atomicMin(&s_gkey[s & 1], (oi << 15) | p);
        }
      }
    }
    __syncthreads();                                  // barrier 2
    const int key = s_gkey[s & 1];
    far_orig = key >> 15;
    spos = key & 32767;
  }
}

// ---------------------------------------------------------------------------
// Gather: [B][NPOINT][3] then [B][NPOINT][128], concatenated flat.
// ---------------------------------------------------------------------------
__global__ __launch_bounds__(256) void gather_kernel(
    const float* __restrict__ xyz, const float* __restrict__ feat,
    const int* __restrict__ fps_idx, float* __restrict__ out) {
  const int lane = threadIdx.x & 31;
  const int sub  = threadIdx.x >> 5;
  const int row  = blockIdx.x * 8 + sub;
  const int b    = row >> 11;
  const int src  = fps_idx[row];

  const float4* __restrict__ f =
      reinterpret_cast<const float4*>(feat + ((size_t)b * NPTS + src) * C_FEAT);
  float4* __restrict__ o =
      reinterpret_cast<float4*>(out + (size_t)BATCH * NPOINT * 3 +
                                (size_t)row * C_FEAT);
  o[lane] = f[lane];
  if (lane < 3) {
    out[(size_t)row * 3 + lane] = xyz[((size_t)b * NPTS + src) * 3 + lane];
  }
}

extern "C" void kernel_launch(void* const* d_in, const int* in_sizes, int n_in,
                              void* d_out, int out_size, void* d_ws, size_t ws_size,
                              hipStream_t stream) {
  (void)in_sizes; (void)n_in; (void)out_size; (void)ws_size;
  const float* xyz  = (const float*)d_in[0];
  const float* feat = (const float*)d_in[1];
  float* out = (float*)d_out;

  char* ws = (char*)d_ws;
  int*   fps_idx = (int*)ws;                         // 128 KB
  int*   pos0    = (int*)(ws + (1u << 17));          // @128KB
  float* x_t     = (float*)(ws + (2u << 20));        // 2 MB each
  float* y_t     = (float*)(ws + (4u << 20));
  float* z_t     = (float*)(ws + (6u << 20));
  int*   oidx_t  = (int*)(ws + (8u << 20));          // ends @10MB

  sort_kernel<<<BATCH, NTH, 0, stream>>>(xyz, x_t, y_t, z_t, oidx_t, pos0);
  fps_kernel<<<BATCH, NTH, 0, stream>>>(x_t, y_t, z_t, oidx_t, pos0, fps_idx);
  gather_kernel<<<(BATCH * NPOINT) / 8, 256, 0, stream>>>(xyz, feat, fps_idx, out);
}

// Round 11
// 14510.046 us; speedup vs baseline: 1.9629x; 1.9629x over previous
//
#include <hip/hip_runtime.h>

#define BATCH   16
#define NPTS    32768
#define NPOINT  2048
#define C_FEAT  128
#define NCELL   4096          // 16x16x16 grid, id (qx<<8)|(qy<<4)|qz
#define NTH     1024
#define NW      16
#define WLCAP   2048          // non-empty cells ~1500 => no overflow expected

// ===========================================================================
// Round 11 = round 10 (LDS-resident lazy FPS) minus the hang candidates:
//  - NO unbounded claim loop / width-16 shfl broadcast: phase B statically
//    stripes the worklist across 64 16-lane groups (all loops bounded).
//  - LDS 163.4KB -> 156.1KB (4KB below the 160KiB ceiling).
//  - pass 2 simplified to owned-cell scan (drops mcell machinery).
// Exactness (unchanged): skip cell only if r2*0.999 > cmax, r2 from
// eps-widened analytic bbox (quantization err ~1.5e-7 << 1e-4 widening)
// => skipped dmin bits provably unchanged; updates use the r7-VERIFIED
// reference pipeline fmaf(dz,dz,fmaf(dy,dy,dx*dx)); argmax = exact max of
// cellmax then min ORIGINAL index among dmin==M == np.argmax first-occurrence.
// min/fmax are exact & commutative => nondeterministic sort scatter order
// cannot change any output bit.
// ws: [fps_idx 128KB @0][cellstart 262KB @128KB][pts 8MB @1MB]
// ===========================================================================

__device__ __forceinline__ int cell_raw(float x, float y, float z) {
  int qx = min(15, max(0, (int)((x + 5.0f) * 1.6f)));
  int qy = min(15, max(0, (int)((y + 5.0f) * 1.6f)));
  int qz = min(15, max(0, (int)((z + 5.0f) * 1.6f)));
  return (qx << 8) | (qy << 4) | qz;
}

// min possible dist^2 from (cx,cy,cz) to eps-widened bbox of cell c
__device__ __forceinline__ float cell_r2(int c, float cx, float cy, float cz) {
  const int qx = c >> 8, qy = (c >> 4) & 15, qz = c & 15;
  float lx = -5.0f + 0.625f * qx - 1e-4f, hx = lx + 0.6252f;
  float ly = -5.0f + 0.625f * qy - 1e-4f, hy = ly + 0.6252f;
  float lz = -5.0f + 0.625f * qz - 1e-4f, hz = lz + 0.6252f;
  if (qx == 0) lx = -1e30f;  if (qx == 15) hx = 1e30f;
  if (qy == 0) ly = -1e30f;  if (qy == 15) hy = 1e30f;
  if (qz == 0) lz = -1e30f;  if (qz == 15) hz = 1e30f;
  const float ddx = fmaxf(fmaxf(lx - cx, cx - hx), 0.0f);
  const float ddy = fmaxf(fmaxf(ly - cy, cy - hy), 0.0f);
  const float ddz = fmaxf(fmaxf(lz - cz, cz - hz), 0.0f);
  return ddx * ddx + ddy * ddy + ddz * ddz;
}

// ---------------------------------------------------------------------------
// Counting sort by cell (one block per batch): pts = (x,y,z,bitcast(origidx))
// contiguous per cell; cellstart[NCELL+1] exclusive offsets.
// ---------------------------------------------------------------------------
__global__ __launch_bounds__(NTH) void sort_kernel(
    const float* __restrict__ xyz, float4* __restrict__ pts,
    int* __restrict__ cellstart) {
  const int b = blockIdx.x, t = threadIdx.x, lane = t & 63;
  const float* __restrict__ base = xyz + (size_t)b * NPTS * 3;
  __shared__ unsigned bins[NCELL];
  __shared__ unsigned wsum[NW];

  for (int i = t; i < NCELL; i += NTH) bins[i] = 0u;
  __syncthreads();
  for (int k = 0; k < 32; ++k) {
    const int p = k * NTH + t;
    atomicAdd(&bins[cell_raw(base[p*3], base[p*3+1], base[p*3+2])], 1u);
  }
  __syncthreads();

  unsigned c0 = bins[4*t], c1 = bins[4*t+1], c2 = bins[4*t+2], c3 = bins[4*t+3];
  const unsigned mysum = c0 + c1 + c2 + c3;
  unsigned acc = mysum;
#pragma unroll
  for (int d = 1; d < 64; d <<= 1) {
    unsigned n = __shfl_up(acc, d);
    if (lane >= d) acc += n;
  }
  if (lane == 63) wsum[t >> 6] = acc;
  __syncthreads();
  unsigned woff = 0;
  for (int w = 0; w < (t >> 6); ++w) woff += wsum[w];
  unsigned run = woff + acc - mysum;
  int* cs = cellstart + b * (NCELL + 1);
  bins[4*t]   = run; cs[4*t]   = (int)run; run += c0;
  bins[4*t+1] = run; cs[4*t+1] = (int)run; run += c1;
  bins[4*t+2] = run; cs[4*t+2] = (int)run; run += c2;
  bins[4*t+3] = run; cs[4*t+3] = (int)run;
  if (t == 0) cs[NCELL] = NPTS;
  __syncthreads();

  float4* __restrict__ pb = pts + (size_t)b * NPTS;
  for (int k = 0; k < 32; ++k) {
    const int p = k * NTH + t;
    const float x = base[p*3], y = base[p*3+1], z = base[p*3+2];
    const unsigned pos = atomicAdd(&bins[cell_raw(x, y, z)], 1u);
    pb[pos] = make_float4(x, y, z, __int_as_float(p));
  }
}

// ---------------------------------------------------------------------------
// LDS-resident lazy FPS, all loops statically bounded. One block per batch.
// ---------------------------------------------------------------------------
__global__ __launch_bounds__(NTH) void fps_kernel(
    const float4* __restrict__ pts_g, const int* __restrict__ cellstart,
    const float* __restrict__ xyz, int* __restrict__ fps_idx) {
  const int b = blockIdx.x, t = threadIdx.x, lane = t & 63, w = t >> 6;
  const int g = t >> 4, gl = t & 15;   // 64 groups of 16 lanes
  const float4* __restrict__ P = pts_g + (size_t)b * NPTS;
  const int* __restrict__ CS = cellstart + b * (NCELL + 1);

  __shared__ float          dmin[NPTS];     // 128 KB
  __shared__ float          cmax[NCELL];    // 16 KB
  __shared__ unsigned short cs16[NCELL];    // 8 KB
  __shared__ unsigned short wl[WLCAP];      // 4 KB
  __shared__ float s_wmax[NW];
  __shared__ float s_cent[3];
  __shared__ int   s_far, s_cnt, s_key;

  for (int k = 0; k < 32; ++k) dmin[k * NTH + t] = 1e10f;
#pragma unroll
  for (int j = 0; j < 4; ++j) {
    const int c = t + j * NTH;
    const int a0 = CS[c], a1 = CS[c + 1];
    cs16[c] = (unsigned short)a0;
    cmax[c] = (a1 > a0) ? 1e10f : -1e30f;   // empty cells never win
  }
  if (t == 0) {
    const float* b0 = xyz + (size_t)b * NPTS * 3;
    s_cent[0] = b0[0]; s_cent[1] = b0[1]; s_cent[2] = b0[2];
    s_far = 0; s_cnt = 0; s_key = 0x7fffffff;
  }
  __syncthreads();

  for (int s = 0; s < NPOINT; ++s) {
    const float cx = s_cent[0], cy = s_cent[1], cz = s_cent[2];
    if (t == 0) fps_idx[b * NPOINT + s] = s_far;
    if (t == 2) s_key = 0x7fffffff;   // prev value consumed before last barrier

    // ---- phase A: needy-cell compaction (prune vs analytic bbox) ----
    unsigned nm = 0;
#pragma unroll
    for (int j = 0; j < 4; ++j) {
      const int c = t + j * NTH;
      const float cm = cmax[c];
      if (cm > -1e29f && !(cell_r2(c, cx, cy, cz) * 0.999f > cm)) nm |= 1u << j;
    }
    const int myn = __popc(nm);
    int accn = myn;
#pragma unroll
    for (int d = 1; d < 64; d <<= 1) {
      int n = __shfl_up(accn, d);
      if (lane >= d) accn += n;
    }
    int wbase = 0;
    if (lane == 63) wbase = atomicAdd(&s_cnt, accn);
    wbase = __shfl(wbase, 63);
    int wp = wbase + accn - myn;
#pragma unroll
    for (int j = 0; j < 4; ++j)
      if (nm & (1u << j)) {
        if (wp < WLCAP) wl[wp] = (unsigned short)(t + j * NTH);
        ++wp;
      }
    __syncthreads();                                          // B1

    // ---- phase B: update needy cells, 16-lane groups, STATIC striping ----
    const int C = s_cnt;
    if (C <= WLCAP) {
      for (int e = g; e < C; e += 64) {
        const int c = (int)wl[e];
        const int st = (int)cs16[c];
        const int en = (c == NCELL - 1) ? NPTS : (int)cs16[c + 1];
        float vm = -1e30f;
        for (int i = st + gl; i < en; i += 16) {
          const float4 q = P[i];
          const float dx = q.x - cx, dy = q.y - cy, dz = q.z - cz;
          const float d = __builtin_fmaf(dz, dz, __builtin_fmaf(dy, dy, dx*dx));
          const float nd = fminf(dmin[i], d);
          dmin[i] = nd;
          vm = fmaxf(vm, nd);
        }
#pragma unroll
        for (int off = 8; off > 0; off >>= 1)
          vm = fmaxf(vm, __shfl_xor(vm, off));
        if (gl == 0) cmax[c] = vm;
      }
    } else {  // safety fallback (expected never): rescan all cells, same test
      for (int j = 0; j < 64; ++j) {
        const int c = (j << 6) | g;
        const float cm = cmax[c];
        if (cm < -1e29f) continue;
        if (cell_r2(c, cx, cy, cz) * 0.999f > cm) continue;
        const int st = (int)cs16[c];
        const int en = (c == NCELL - 1) ? NPTS : (int)cs16[c + 1];
        float vm = -1e30f;
        for (int i = st + gl; i < en; i += 16) {
          const float4 q = P[i];
          const float dx = q.x - cx, dy = q.y - cy, dz = q.z - cz;
          const float d = __builtin_fmaf(dz, dz, __builtin_fmaf(dy, dy, dx*dx));
          const float nd = fminf(dmin[i], d);
          dmin[i] = nd;
          vm = fmaxf(vm, nd);
        }
#pragma unroll
        for (int off = 8; off > 0; off >>= 1)
          vm = fmaxf(vm, __shfl_xor(vm, off));
        if (gl == 0) cmax[c] = vm;
      }
    }
    __syncthreads();                                          // B2

    // ---- phase C: global max of cellmax ----
    float v = -1e30f;
#pragma unroll
    for (int j = 0; j < 4; ++j) v = fmaxf(v, cmax[t + j * NTH]);
#pragma unroll
    for (int off = 32; off > 0; off >>= 1) v = fmaxf(v, __shfl_xor(v, off));
    if (lane == 0) s_wmax[w] = v;
    __syncthreads();                                          // B3
    float M = s_wmax[lane & 15];
#pragma unroll
    for (int off = 8; off > 0; off >>= 1) M = fmaxf(M, __shfl_xor(M, off));

    // ---- pass 2: min ORIGINAL index among dmin == M (owned cells only) ----
    int boi = 0x7fffffff;
    float bx = 0.f, by = 0.f, bz = 0.f;
#pragma unroll
    for (int j = 0; j < 4; ++j) {
      const int c = t + j * NTH;
      if (cmax[c] == M) {
        const int st = (int)cs16[c];
        const int en = (c == NCELL - 1) ? NPTS : (int)cs16[c + 1];
        for (int i = st; i < en; ++i) {
          if (dmin[i] == M) {
            const float4 q = P[i];
            const int oi = __float_as_int(q.w);
            if (oi < boi) { boi = oi; bx = q.x; by = q.y; bz = q.z; }
          }
        }
      }
    }
    if (boi != 0x7fffffff) atomicMin(&s_key, boi);
    __syncthreads();                                          // B4

    const int winner = s_key;
    if (boi == winner && boi != 0x7fffffff) {  // unique thread (cells disjoint)
      s_cent[0] = bx; s_cent[1] = by; s_cent[2] = bz;
      s_far = winner;
    }
    if (t == 1) s_cnt = 0;
    __syncthreads();                                          // B5
  }
}

// ---------------------------------------------------------------------------
// Gather: [B][NPOINT][3] then [B][NPOINT][128], concatenated flat.
// ---------------------------------------------------------------------------
__global__ __launch_bounds__(256) void gather_kernel(
    const float* __restrict__ xyz, const float* __restrict__ feat,
    const int* __restrict__ fps_idx, float* __restrict__ out) {
  const int lane = threadIdx.x & 31;
  const int sub  = threadIdx.x >> 5;
  const int row  = blockIdx.x * 8 + sub;
  const int b    = row >> 11;
  const int src  = fps_idx[row];

  const float4* __restrict__ f =
      reinterpret_cast<const float4*>(feat + ((size_t)b * NPTS + src) * C_FEAT);
  float4* __restrict__ o =
      reinterpret_cast<float4*>(out + (size_t)BATCH * NPOINT * 3 +
                                (size_t)row * C_FEAT);
  o[lane] = f[lane];
  if (lane < 3) {
    out[(size_t)row * 3 + lane] = xyz[((size_t)b * NPTS + src) * 3 + lane];
  }
}

extern "C" void kernel_launch(void* const* d_in, const int* in_sizes, int n_in,
                              void* d_out, int out_size, void* d_ws, size_t ws_size,
                              hipStream_t stream) {
  (void)in_sizes; (void)n_in; (void)out_size; (void)ws_size;
  const float* xyz  = (const float*)d_in[0];
  const float* feat = (const float*)d_in[1];
  float* out = (float*)d_out;

  char* ws = (char*)d_ws;
  int*    fps_idx   = (int*)ws;                     // 128 KB @ 0
  int*    cellstart = (int*)(ws + (1u << 17));      // 262 KB @ 128KB
  float4* pts       = (float4*)(ws + (1u << 20));   // 8 MB @ 1MB

  sort_kernel<<<BATCH, NTH, 0, stream>>>(xyz, pts, cellstart);
  fps_kernel<<<BATCH, NTH, 0, stream>>>(pts, cellstart, xyz, fps_idx);
  gather_kernel<<<(BATCH * NPOINT) / 8, 256, 0, stream>>>(xyz, feat, fps_idx, out);
}

// Round 12
// 14067.157 us; speedup vs baseline: 2.0247x; 1.0315x over previous
//
#include <hip/hip_runtime.h>

#define BATCH   16
#define NPTS    32768
#define NPOINT  2048
#define C_FEAT  128
#define NCELL   4096          // 16^3 grid over [-4,4], id (qx<<8)|(qy<<4)|qz
#define NTH     1024
#define NW      16

// ===========================================================================
// Round 12 = r11 minus its two latency sinks (evidence: 7.1us/step with only
// 1.0us VALU; serial 1-thread winning-cell scan ~500 LDS reads/step):
//  (1) pass 2 parallelized: phase-C reduce carries (val,min_cell,max_cell);
//      unique-cell fast path scanned by ALL 1024 threads.
//  (2) worklist dropped: groups own 64 contiguous cells, predicate+__ballot
//      +process (bounded bit loop) -> one fewer barrier, no compaction scan.
//  (3) grid tightened to [-4,4] (cell 0.5) -> central cell ~260 pts.
// Exactness invariants unchanged from r11: skip only if r2*0.999 > cmax with
// eps-widened analytic bbox (binning err ~2e-6 << 1e-4 widening); updates use
// the r7-VERIFIED pipeline fmaf(dz,dz,fmaf(dy,dy,dx*dx)); argmax = exact max
// of cellmax then min ORIGINAL index among dmin==M (np first-occurrence);
// min/fmax exact+commutative => scatter order cannot change output bits.
// ws: [fps_idx 128KB @0][cellstart 262KB @128KB][pts 8MB @1MB]
// ===========================================================================

#define GRID_LO  (-4.0f)
#define GRID_IW  (2.0f)       // 1/cellwidth
#define GRID_W   (0.5f)

__device__ __forceinline__ int cell_raw(float x, float y, float z) {
  int qx = min(15, max(0, (int)((x - GRID_LO) * GRID_IW)));
  int qy = min(15, max(0, (int)((y - GRID_LO) * GRID_IW)));
  int qz = min(15, max(0, (int)((z - GRID_LO) * GRID_IW)));
  return (qx << 8) | (qy << 4) | qz;
}

// min possible dist^2 from (cx,cy,cz) to eps-widened bbox of cell c
__device__ __forceinline__ float cell_r2(int c, float cx, float cy, float cz) {
  const int qx = c >> 8, qy = (c >> 4) & 15, qz = c & 15;
  float lx = GRID_LO + GRID_W * qx - 1e-4f, hx = lx + (GRID_W + 2e-4f);
  float ly = GRID_LO + GRID_W * qy - 1e-4f, hy = ly + (GRID_W + 2e-4f);
  float lz = GRID_LO + GRID_W * qz - 1e-4f, hz = lz + (GRID_W + 2e-4f);
  if (qx == 0) lx = -1e30f;  if (qx == 15) hx = 1e30f;
  if (qy == 0) ly = -1e30f;  if (qy == 15) hy = 1e30f;
  if (qz == 0) lz = -1e30f;  if (qz == 15) hz = 1e30f;
  const float ddx = fmaxf(fmaxf(lx - cx, cx - hx), 0.0f);
  const float ddy = fmaxf(fmaxf(ly - cy, cy - hy), 0.0f);
  const float ddz = fmaxf(fmaxf(lz - cz, cz - hz), 0.0f);
  return ddx * ddx + ddy * ddy + ddz * ddz;
}

// ---------------------------------------------------------------------------
// Counting sort by cell (one block per batch): pts = (x,y,z,bitcast(origidx))
// contiguous per cell; cellstart[NCELL+1] exclusive offsets.
// ---------------------------------------------------------------------------
__global__ __launch_bounds__(NTH) void sort_kernel(
    const float* __restrict__ xyz, float4* __restrict__ pts,
    int* __restrict__ cellstart) {
  const int b = blockIdx.x, t = threadIdx.x, lane = t & 63;
  const float* __restrict__ base = xyz + (size_t)b * NPTS * 3;
  __shared__ unsigned bins[NCELL];
  __shared__ unsigned wsum[NW];

  for (int i = t; i < NCELL; i += NTH) bins[i] = 0u;
  __syncthreads();
  for (int k = 0; k < 32; ++k) {
    const int p = k * NTH + t;
    atomicAdd(&bins[cell_raw(base[p*3], base[p*3+1], base[p*3+2])], 1u);
  }
  __syncthreads();

  unsigned c0 = bins[4*t], c1 = bins[4*t+1], c2 = bins[4*t+2], c3 = bins[4*t+3];
  const unsigned mysum = c0 + c1 + c2 + c3;
  unsigned acc = mysum;
#pragma unroll
  for (int d = 1; d < 64; d <<= 1) {
    unsigned n = __shfl_up(acc, d);
    if (lane >= d) acc += n;
  }
  if (lane == 63) wsum[t >> 6] = acc;
  __syncthreads();
  unsigned woff = 0;
  for (int w = 0; w < (t >> 6); ++w) woff += wsum[w];
  unsigned run = woff + acc - mysum;
  int* cs = cellstart + b * (NCELL + 1);
  bins[4*t]   = run; cs[4*t]   = (int)run; run += c0;
  bins[4*t+1] = run; cs[4*t+1] = (int)run; run += c1;
  bins[4*t+2] = run; cs[4*t+2] = (int)run; run += c2;
  bins[4*t+3] = run; cs[4*t+3] = (int)run;
  if (t == 0) cs[NCELL] = NPTS;
  __syncthreads();

  float4* __restrict__ pb = pts + (size_t)b * NPTS;
  for (int k = 0; k < 32; ++k) {
    const int p = k * NTH + t;
    const float x = base[p*3], y = base[p*3+1], z = base[p*3+2];
    const unsigned pos = atomicAdd(&bins[cell_raw(x, y, z)], 1u);
    pb[pos] = make_float4(x, y, z, __int_as_float(p));
  }
}

// ---------------------------------------------------------------------------
// LDS-resident lazy FPS; 4 barriers/step; all loops bounded.
// ---------------------------------------------------------------------------
__global__ __launch_bounds__(NTH) void fps_kernel(
    const float4* __restrict__ pts_g, const int* __restrict__ cellstart,
    const float* __restrict__ xyz, int* __restrict__ fps_idx) {
  const int b = blockIdx.x, t = threadIdx.x, lane = t & 63, w = t >> 6;
  const int g = t >> 4, gl = t & 15, sub = (t >> 4) & 3;  // 64 groups x 16
  const float4* __restrict__ P = pts_g + (size_t)b * NPTS;
  const int* __restrict__ CS = cellstart + b * (NCELL + 1);

  __shared__ float          dmin[NPTS];     // 128 KB
  __shared__ float          cmax[NCELL];    // 16 KB
  __shared__ unsigned short cs16[NCELL];    // 8 KB
  __shared__ float s_wv[NW];
  __shared__ int   s_wmn[NW], s_wmx[NW];
  __shared__ float s_cent[3];
  __shared__ int   s_far, s_key[2];

  for (int k = 0; k < 32; ++k) dmin[k * NTH + t] = 1e10f;
#pragma unroll
  for (int j = 0; j < 4; ++j) {
    const int c = t + j * NTH;
    const int a0 = CS[c], a1 = CS[c + 1];
    cs16[c] = (unsigned short)a0;
    cmax[c] = (a1 > a0) ? 1e10f : -1e30f;   // empty cells never win
  }
  if (t == 0) {
    const float* b0 = xyz + (size_t)b * NPTS * 3;
    s_cent[0] = b0[0]; s_cent[1] = b0[1]; s_cent[2] = b0[2];
    s_far = 0; s_key[0] = 0x7fffffff; s_key[1] = 0x7fffffff;
  }
  __syncthreads();

  for (int s = 0; s < NPOINT; ++s) {
    const float cx = s_cent[0], cy = s_cent[1], cz = s_cent[2];
    if (t == 0) {
      fps_idx[b * NPOINT + s] = s_far;
      s_key[(s + 1) & 1] = 0x7fffffff;   // other slot; consumers done last step
    }

    // ---- phase 1: groups process their own needy cells (no worklist) ----
#pragma unroll
    for (int r = 0; r < 4; ++r) {
      const int c = (g << 6) + (r << 4) + gl;       // conflict-free cmax read
      const float cm = cmax[c];
      const bool need =
          (cm > -1e29f) && !(cell_r2(c, cx, cy, cz) * 0.999f > cm);
      const unsigned long long bal = __ballot(need);
      unsigned m = (unsigned)((bal >> (sub << 4)) & 0xffffull);
      for (int it = 0; it < 16 && m; ++it) {        // bounded bit loop
        const int jb = __builtin_ctz(m); m &= m - 1u;
        const int c2 = (g << 6) + (r << 4) + jb;
        const int st = (int)cs16[c2];
        const int en = (c2 == NCELL - 1) ? NPTS : (int)cs16[c2 + 1];
        float vm = -1e30f;
        for (int i = st + gl; i < en; i += 16) {
          const float4 q = P[i];
          const float dx = q.x - cx, dy = q.y - cy, dz = q.z - cz;
          // EXACT reference pipeline (verified round 7):
          const float d = __builtin_fmaf(dz, dz, __builtin_fmaf(dy, dy, dx*dx));
          const float nd = fminf(dmin[i], d);
          dmin[i] = nd;
          vm = fmaxf(vm, nd);
        }
#pragma unroll
        for (int off = 8; off > 0; off >>= 1)
          vm = fmaxf(vm, __shfl_xor(vm, off));      // stays within 16-lane grp
        if (gl == 0) cmax[c2] = vm;
      }
    }
    __syncthreads();                                          // B1

    // ---- phase 2: (max value, min cell, max cell) reduce ----
    float v = -1e30f; int mn = 0x7fffffff, mx = -1;
#pragma unroll
    for (int j = 0; j < 4; ++j) {
      const int c = t + j * NTH;
      const float cv = cmax[c];
      if (cv > v)       { v = cv; mn = c; mx = c; }
      else if (cv == v) { mn = min(mn, c); mx = max(mx, c); }
    }
#pragma unroll
    for (int off = 32; off > 0; off >>= 1) {
      const float ov = __shfl_xor(v, off);
      const int omn = __shfl_xor(mn, off), omx = __shfl_xor(mx, off);
      if (ov > v)       { v = ov; mn = omn; mx = omx; }
      else if (ov == v) { mn = min(mn, omn); mx = max(mx, omx); }
    }
    if (lane == 0) { s_wv[w] = v; s_wmn[w] = mn; s_wmx[w] = mx; }
    __syncthreads();                                          // B2
    v = s_wv[lane & 15]; mn = s_wmn[lane & 15]; mx = s_wmx[lane & 15];
#pragma unroll
    for (int off = 8; off > 0; off >>= 1) {
      const float ov = __shfl_xor(v, off);
      const int omn = __shfl_xor(mn, off), omx = __shfl_xor(mx, off);
      if (ov > v)       { v = ov; mn = omn; mx = omx; }
      else if (ov == v) { mn = min(mn, omn); mx = max(mx, omx); }
    }
    const float M = v;   // block-uniform

    // ---- phase 3: min ORIGINAL index among dmin == M ----
    int boi = 0x7fffffff; float bx = 0.f, by = 0.f, bz = 0.f;
    if (mn == mx) {
      // fast path (unique winning cell): ALL threads stride its range
      const int st = (int)cs16[mn];
      const int en = (mn == NCELL - 1) ? NPTS : (int)cs16[mn + 1];
      for (int i = st + t; i < en; i += NTH) {
        if (dmin[i] == M) {
          const float4 q = P[i];
          const int oi = __float_as_int(q.w);
          if (oi < boi) { boi = oi; bx = q.x; by = q.y; bz = q.z; }
        }
      }
    } else {
      // rare cross-cell tie: bounded owned-cell serial scan
#pragma unroll
      for (int j = 0; j < 4; ++j) {
        const int c = t + j * NTH;
        if (cmax[c] == M) {
          const int st = (int)cs16[c];
          const int en = (c == NCELL - 1) ? NPTS : (int)cs16[c + 1];
          for (int i = st; i < en; ++i) {
            if (dmin[i] == M) {
              const float4 q = P[i];
              const int oi = __float_as_int(q.w);
              if (oi < boi) { boi = oi; bx = q.x; by = q.y; bz = q.z; }
            }
          }
        }
      }
    }
    if (boi != 0x7fffffff) atomicMin(&s_key[s & 1], boi);
    __syncthreads();                                          // B3

    if (boi == s_key[s & 1] && boi != 0x7fffffff) {  // unique winner thread
      s_cent[0] = bx; s_cent[1] = by; s_cent[2] = bz;
      s_far = boi;
    }
    __syncthreads();                                          // B4
  }
}

// ---------------------------------------------------------------------------
// Gather: [B][NPOINT][3] then [B][NPOINT][128], concatenated flat.
// ---------------------------------------------------------------------------
__global__ __launch_bounds__(256) void gather_kernel(
    const float* __restrict__ xyz, const float* __restrict__ feat,
    const int* __restrict__ fps_idx, float* __restrict__ out) {
  const int lane = threadIdx.x & 31;
  const int sub  = threadIdx.x >> 5;
  const int row  = blockIdx.x * 8 + sub;
  const int b    = row >> 11;
  const int src  = fps_idx[row];

  const float4* __restrict__ f =
      reinterpret_cast<const float4*>(feat + ((size_t)b * NPTS + src) * C_FEAT);
  float4* __restrict__ o =
      reinterpret_cast<float4*>(out + (size_t)BATCH * NPOINT * 3 +
                                (size_t)row * C_FEAT);
  o[lane] = f[lane];
  if (lane < 3) {
    out[(size_t)row * 3 + lane] = xyz[((size_t)b * NPTS + src) * 3 + lane];
  }
}

extern "C" void kernel_launch(void* const* d_in, const int* in_sizes, int n_in,
                              void* d_out, int out_size, void* d_ws, size_t ws_size,
                              hipStream_t stream) {
  (void)in_sizes; (void)n_in; (void)out_size; (void)ws_size;
  const float* xyz  = (const float*)d_in[0];
  const float* feat = (const float*)d_in[1];
  float* out = (float*)d_out;

  char* ws = (char*)d_ws;
  int*    fps_idx   = (int*)ws;                     // 128 KB @ 0
  int*    cellstart = (int*)(ws + (1u << 17));      // 262 KB @ 128KB
  float4* pts       = (float4*)(ws + (1u << 20));   // 8 MB @ 1MB

  sort_kernel<<<BATCH, NTH, 0, stream>>>(xyz, pts, cellstart);
  fps_kernel<<<BATCH, NTH, 0, stream>>>(pts, cellstart, xyz, fps_idx);
  gather_kernel<<<(BATCH * NPOINT) / 8, 256, 0, stream>>>(xyz, feat, fps_idx, out);
}

// Round 13
// 13921.687 us; speedup vs baseline: 2.0458x; 1.0104x over previous
//
#include <hip/hip_runtime.h>

#define BATCH   16
#define NPTS    32768
#define NPOINT  2048
#define C_FEAT  128
#define NX      16
#define NZ      15
#define NCELL   (NX*NX*NZ)        // 3840 cells: 16x16x15 over [-4,4]
#define CPW     (NCELL/16)        // 240 cells per wave
#define NTH     1024
#define NW      16

#define GRID_LO (-4.0f)
#define WXY     0.5f
#define WZ      (8.0f/15.0f)

// ===========================================================================
// Round 13: latency-restructured lazy FPS (math identical to r11/r12).
// r12 lesson: 6.9us/step was DISTRIBUTED latency (16-lane runtime loops with
// dependent LDS RMW chains; 4 barrier-separated phases each adding LDS/L2
// round trips), not one sink. Changes:
//  - wave-per-cell updates (64 lanes, unroll 2): max-cell chain 16 -> 4 iters
//  - per-cell (cmax, argkey) MEMOIZATION as monotone-packed u64:
//      pack = f32bits(cmax)<<32 | (0x3FFFFFFF - (origidx<<15|pos))
//    untouched cells stay valid (their dmin unchanged); global argmax = one
//    u64-max tree (nonneg f32 bits monotone; complemented key => min origidx
//    on ties == np.argmax first-occurrence EXACTLY). No dmin==M rescan, no
//    atomics, no s_cent round-trip -> 2 barriers/step.
//  - dmin is wave-private; all LDS access contiguous (conflict-light).
// Exactness: prune only if r2*0.999 > cmax (bbox eps-widened 1e-4 >> 1e-6
// binning err); updates use r7-VERIFIED fmaf(dz,dz,fmaf(dy,dy,dx*dx)).
// ws: [fps_idx 128KB @0][pos0 @128KB][cellstart @256KB][pts 8MB @1MB]
// ===========================================================================

__device__ __forceinline__ int cell_of(float x, float y, float z) {
  int qx = min(NX - 1, max(0, (int)((x - GRID_LO) * 2.0f)));
  int qy = min(NX - 1, max(0, (int)((y - GRID_LO) * 2.0f)));
  int qz = min(NZ - 1, max(0, (int)((z - GRID_LO) * 1.875f)));
  return (qx * NX + qy) * NZ + qz;
}

__device__ __forceinline__ float cell_r2(int c, float cx, float cy, float cz) {
  const int qx = c / (NX * NZ);
  const int rem = c - qx * (NX * NZ);
  const int qy = rem / NZ;
  const int qz = rem - qy * NZ;
  float lx = GRID_LO + WXY * qx - 1e-4f, hx = lx + (WXY + 2e-4f);
  float ly = GRID_LO + WXY * qy - 1e-4f, hy = ly + (WXY + 2e-4f);
  float lz = GRID_LO + WZ * qz - 1e-4f,  hz = lz + (WZ + 2e-4f);
  if (qx == 0) lx = -1e30f;  if (qx == NX - 1) hx = 1e30f;
  if (qy == 0) ly = -1e30f;  if (qy == NX - 1) hy = 1e30f;
  if (qz == 0) lz = -1e30f;  if (qz == NZ - 1) hz = 1e30f;
  const float ddx = fmaxf(fmaxf(lx - cx, cx - hx), 0.0f);
  const float ddy = fmaxf(fmaxf(ly - cy, cy - hy), 0.0f);
  const float ddz = fmaxf(fmaxf(lz - cz, cz - hz), 0.0f);
  return ddx * ddx + ddy * ddy + ddz * ddz;
}

// ---------------------------------------------------------------------------
// Counting sort by cell: pts = (x,y,z,bitcast(origidx)) contiguous per cell.
// bins padded to 4096 (3840..4095 stay zero) so the r12 scan works unchanged.
// ---------------------------------------------------------------------------
__global__ __launch_bounds__(NTH) void sort_kernel(
    const float* __restrict__ xyz, float4* __restrict__ pts,
    int* __restrict__ cellstart, int* __restrict__ pos0) {
  const int b = blockIdx.x, t = threadIdx.x, lane = t & 63;
  const float* __restrict__ base = xyz + (size_t)b * NPTS * 3;
  __shared__ unsigned bins[4096];
  __shared__ unsigned wsum[NW];

  for (int i = t; i < 4096; i += NTH) bins[i] = 0u;
  __syncthreads();
  for (int k = 0; k < 32; ++k) {
    const int p = k * NTH + t;
    atomicAdd(&bins[cell_of(base[p*3], base[p*3+1], base[p*3+2])], 1u);
  }
  __syncthreads();

  unsigned c0 = bins[4*t], c1 = bins[4*t+1], c2 = bins[4*t+2], c3 = bins[4*t+3];
  const unsigned mysum = c0 + c1 + c2 + c3;
  unsigned acc = mysum;
#pragma unroll
  for (int d = 1; d < 64; d <<= 1) {
    unsigned n = __shfl_up(acc, d);
    if (lane >= d) acc += n;
  }
  if (lane == 63) wsum[t >> 6] = acc;
  __syncthreads();
  unsigned woff = 0;
  for (int w = 0; w < (t >> 6); ++w) woff += wsum[w];
  unsigned run = woff + acc - mysum;
  int* cs = cellstart + b * 4097;
  bins[4*t]   = run; cs[4*t]   = (int)run; run += c0;
  bins[4*t+1] = run; cs[4*t+1] = (int)run; run += c1;
  bins[4*t+2] = run; cs[4*t+2] = (int)run; run += c2;
  bins[4*t+3] = run; cs[4*t+3] = (int)run;
  if (t == 0) cs[4096] = NPTS;
  __syncthreads();

  float4* __restrict__ pb = pts + (size_t)b * NPTS;
  for (int k = 0; k < 32; ++k) {
    const int p = k * NTH + t;
    const float x = base[p*3], y = base[p*3+1], z = base[p*3+2];
    const unsigned pos = atomicAdd(&bins[cell_of(x, y, z)], 1u);
    pb[pos] = make_float4(x, y, z, __int_as_float(p));
    if (p == 0) pos0[b] = (int)pos;
  }
}

__device__ __forceinline__ unsigned long long u64max(unsigned long long a,
                                                     unsigned long long b) {
  return a > b ? a : b;
}

// ---------------------------------------------------------------------------
// Lazy FPS: wave-per-cell updates, memoized per-cell argmax packs,
// 2 barriers per step. One block per batch.
// ---------------------------------------------------------------------------
__global__ __launch_bounds__(NTH) void fps_kernel(
    const float4* __restrict__ pts_g, const int* __restrict__ cellstart,
    const int* __restrict__ pos0, int* __restrict__ fps_idx) {
  const int b = blockIdx.x, t = threadIdx.x, lane = t & 63, w = t >> 6;
  const float4* __restrict__ P = pts_g + (size_t)b * NPTS;
  const int* __restrict__ CS = cellstart + b * 4097;

  __shared__ float              dmin[NPTS];      // 128 KB (wave-private slices)
  __shared__ unsigned long long pack[NCELL];     // 30 KB
  __shared__ unsigned long long s_red[NW];       // 128 B

  // init dmin
  for (int k = 0; k < 32; ++k) dmin[k * NTH + t] = 1e10f;

  // cache own cells' [st,en) in registers (slot r: cell = w*CPW + r*64 + lane)
  int str[4], enr[4];
#pragma unroll
  for (int r = 0; r < 4; ++r) {
    const int idx = r * 64 + lane;
    const bool valid = idx < CPW;
    const int c = w * CPW + idx;
    str[r] = valid ? CS[c] : 0;
    enr[r] = valid ? CS[c + 1] : 0;
  }

  // init packs for own cells: cmax=1e10, key = min (origidx<<15|pos) in cell
#pragma unroll
  for (int r = 0; r < 4; ++r) {
    const int idx = r * 64 + lane;
    const bool valid = idx < CPW;
    const bool occ = valid && (enr[r] > str[r]);
    if (valid && !occ) pack[w * CPW + idx] = 0ull;   // empty: never wins
    unsigned long long m = __ballot(occ);
    while (m) {
      const int hi = __builtin_ctzll(m); m &= m - 1;
      const int c2 = w * CPW + r * 64 + hi;
      const int st = __shfl(str[r], hi), en = __shfl(enr[r], hi);
      unsigned bk = 0xFFFFFFFFu;
      for (int i = st + lane; i < en; i += 64) {
        const unsigned oi = (unsigned)__float_as_int(P[i].w);
        bk = min(bk, (oi << 15) | (unsigned)i);
      }
#pragma unroll
      for (int off = 32; off > 0; off >>= 1)
        bk = min(bk, (unsigned)__shfl_xor((int)bk, off));
      if (lane == 0)
        pack[c2] = ((unsigned long long)__float_as_uint(1e10f) << 32) |
                   (0x3FFFFFFFu - bk);
    }
  }
  __syncthreads();

  // prime with start index 0 (reference semantics)
  int far = 0;
  int ppos = pos0[b];
  float4 q0 = P[ppos];
  float cx = q0.x, cy = q0.y, cz = q0.z;

  for (int s = 0; s < NPOINT; ++s) {
    if (t == 0) fps_idx[b * NPOINT + s] = far;

    // ---- phase 1: predicate + wave-per-cell updates (own cells only) ----
#pragma unroll
    for (int r = 0; r < 4; ++r) {
      const int idx = r * 64 + lane;
      bool need = false;
      if (idx < CPW) {
        const int c = w * CPW + idx;
        const unsigned long long pk = pack[c];
        if (pk != 0ull) {
          const float cm = __uint_as_float((unsigned)(pk >> 32));
          need = !(cell_r2(c, cx, cy, cz) * 0.999f > cm);
        }
      }
      unsigned long long m = __ballot(need);
      while (m) {
        const int hi = __builtin_ctzll(m); m &= m - 1;
        const int c2 = w * CPW + r * 64 + hi;
        const int st = __shfl(str[r], hi), en = __shfl(enr[r], hi);
        float vm = -1.0f;
        unsigned bk = 0xFFFFFFFFu;
#pragma unroll 2
        for (int i = st + lane; i < en; i += 64) {
          const float4 q = P[i];
          const float dx = q.x - cx, dy = q.y - cy, dz = q.z - cz;
          // EXACT reference pipeline (verified round 7):
          const float d = __builtin_fmaf(dz, dz, __builtin_fmaf(dy, dy, dx*dx));
          const float nd = fminf(dmin[i], d);
          dmin[i] = nd;
          const unsigned key = ((unsigned)__float_as_int(q.w) << 15) | (unsigned)i;
          if (nd > vm)       { vm = nd; bk = key; }
          else if (nd == vm) { bk = min(bk, key); }
        }
        // wave (val,key) argmax reduce, tie -> min key (= min origidx)
#pragma unroll
        for (int off = 32; off > 0; off >>= 1) {
          const float ov = __shfl_xor(vm, off);
          const unsigned obk = (unsigned)__shfl_xor((int)bk, off);
          if (ov > vm)       { vm = ov; bk = obk; }
          else if (ov == vm) { bk = min(bk, obk); }
        }
        if (lane == 0)
          pack[c2] = ((unsigned long long)__float_as_uint(vm) << 32) |
                     (0x3FFFFFFFu - bk);
      }
    }
    __syncthreads();                                          // B1

    // ---- phase 2: one u64-max tree over all cell packs ----
    unsigned long long p = pack[t];
    p = u64max(p, pack[t + 1024]);
    p = u64max(p, pack[t + 2048]);
    if (t < NCELL - 3072) p = u64max(p, pack[t + 3072]);
#pragma unroll
    for (int off = 32; off > 0; off >>= 1) {
      const unsigned lo = (unsigned)p, hi2 = (unsigned)(p >> 32);
      const unsigned olo = (unsigned)__shfl_xor((int)lo, off);
      const unsigned ohi = (unsigned)__shfl_xor((int)hi2, off);
      p = u64max(p, ((unsigned long long)ohi << 32) | olo);
    }
    if (lane == 0) s_red[w] = p;
    __syncthreads();                                          // B2
    p = s_red[lane & 15];
#pragma unroll
    for (int off = 8; off > 0; off >>= 1) {
      const unsigned lo = (unsigned)p, hi2 = (unsigned)(p >> 32);
      const unsigned olo = (unsigned)__shfl_xor((int)lo, off);
      const unsigned ohi = (unsigned)__shfl_xor((int)hi2, off);
      p = u64max(p, ((unsigned long long)ohi << 32) | olo);
    }
    // uniform winner: decode key, fetch coords via broadcast L2 load
    const unsigned key = 0x3FFFFFFFu - (unsigned)(p & 0x3FFFFFFFu);
    far  = (int)(key >> 15);
    ppos = (int)(key & 0x7FFFu);
    const float4 qn = P[ppos];
    cx = qn.x; cy = qn.y; cz = qn.z;
  }
}

// ---------------------------------------------------------------------------
// Gather: [B][NPOINT][3] then [B][NPOINT][128], concatenated flat.
// ---------------------------------------------------------------------------
__global__ __launch_bounds__(256) void gather_kernel(
    const float* __restrict__ xyz, const float* __restrict__ feat,
    const int* __restrict__ fps_idx, float* __restrict__ out) {
  const int lane = threadIdx.x & 31;
  const int sub  = threadIdx.x >> 5;
  const int row  = blockIdx.x * 8 + sub;
  const int b    = row >> 11;
  const int src  = fps_idx[row];

  const float4* __restrict__ f =
      reinterpret_cast<const float4*>(feat + ((size_t)b * NPTS + src) * C_FEAT);
  float4* __restrict__ o =
      reinterpret_cast<float4*>(out + (size_t)BATCH * NPOINT * 3 +
                                (size_t)row * C_FEAT);
  o[lane] = f[lane];
  if (lane < 3) {
    out[(size_t)row * 3 + lane] = xyz[((size_t)b * NPTS + src) * 3 + lane];
  }
}

extern "C" void kernel_launch(void* const* d_in, const int* in_sizes, int n_in,
                              void* d_out, int out_size, void* d_ws, size_t ws_size,
                              hipStream_t stream) {
  (void)in_sizes; (void)n_in; (void)out_size; (void)ws_size;
  const float* xyz  = (const float*)d_in[0];
  const float* feat = (const float*)d_in[1];
  float* out = (float*)d_out;

  char* ws = (char*)d_ws;
  int*    fps_idx   = (int*)ws;                     // 128 KB @ 0
  int*    pos0      = (int*)(ws + (1u << 17));      // 64 B  @ 128KB
  int*    cellstart = (int*)(ws + (1u << 18));      // 262 KB @ 256KB
  float4* pts       = (float4*)(ws + (1u << 20));   // 8 MB  @ 1MB

  sort_kernel<<<BATCH, NTH, 0, stream>>>(xyz, pts, cellstart, pos0);
  fps_kernel<<<BATCH, NTH, 0, stream>>>(pts, cellstart, pos0, fps_idx);
  gather_kernel<<<(BATCH * NPOINT) / 8, 256, 0, stream>>>(xyz, feat, fps_idx, out);
}